// Round 5
// baseline (240.627 us; speedup 1.0000x reference)
//
#include <hip/hip_runtime.h>

#define S_LEN 2048
#define BATCH 2
#define DM    1024
#define NH    16
#define NKV   4
#define HD    64
#define MROWS (BATCH * S_LEN)   // 4096
#define NQKV  1536              // 1024 q + 512 kv

typedef __attribute__((ext_vector_type(8))) short bf16x8;
typedef __attribute__((ext_vector_type(4))) short s16x4;
typedef __attribute__((ext_vector_type(4))) float f32x4;

__device__ __forceinline__ unsigned short f2bf(float f) {
  unsigned int u = __float_as_uint(f);
  u += 0x7FFF + ((u >> 16) & 1);   // RNE
  return (unsigned short)(u >> 16);
}

__device__ __forceinline__ void gload_lds16(const unsigned short* g, unsigned short* l) {
  __builtin_amdgcn_global_load_lds((const __attribute__((address_space(1))) void*)g,
                                   (__attribute__((address_space(3))) void*)l, 16, 0, 0);
}

// ---------------- x -> bf16 ----------------
__global__ __launch_bounds__(256) void cvt_x_kernel(const float* __restrict__ x,
                                                    unsigned short* __restrict__ xb, int n) {
  int i = (blockIdx.x * 256 + threadIdx.x) * 4;
  if (i < n) {
    float4 v = *reinterpret_cast<const float4*>(x + i);
    xb[i + 0] = f2bf(v.x);
    xb[i + 1] = f2bf(v.y);
    xb[i + 2] = f2bf(v.z);
    xb[i + 3] = f2bf(v.w);
  }
}

// ---------------- W (RxC fp32) -> W^T (CxR bf16) ----------------
__global__ __launch_bounds__(256) void transpose_cvt_kernel(const float* __restrict__ in,
                                                            unsigned short* __restrict__ out,
                                                            int R, int C) {
  __shared__ float tile[64][65];
  int r0 = blockIdx.y * 64, c0 = blockIdx.x * 64;
  int t = threadIdx.x;
  int rl = t >> 2, cs = (t & 3) * 16;
#pragma unroll
  for (int k = 0; k < 4; ++k) {
    float4 v = *reinterpret_cast<const float4*>(in + (size_t)(r0 + rl) * C + c0 + cs + 4 * k);
    tile[rl][cs + 4 * k + 0] = v.x;
    tile[rl][cs + 4 * k + 1] = v.y;
    tile[rl][cs + 4 * k + 2] = v.z;
    tile[rl][cs + 4 * k + 3] = v.w;
  }
  __syncthreads();
  int cl = t >> 2, rs = (t & 3) * 16;
  bf16x8 v0, v1;
#pragma unroll
  for (int i = 0; i < 8; ++i) v0[i] = (short)f2bf(tile[rs + i][cl]);
#pragma unroll
  for (int i = 0; i < 8; ++i) v1[i] = (short)f2bf(tile[rs + 8 + i][cl]);
  unsigned short* dst = out + (size_t)(c0 + cl) * R + r0 + rs;
  *reinterpret_cast<bf16x8*>(dst) = v0;
  *reinterpret_cast<bf16x8*>(dst + 8) = v1;
}

// ------- bf16 GEMM, split-K(2), m97 structure: global_load_lds staging -------
__global__ __launch_bounds__(256) void gemm_bt_splitk(const unsigned short* __restrict__ A,
                                                      const unsigned short* __restrict__ BT,
                                                      float* __restrict__ Cp,
                                                      int M, int N, int Kpart, int Ktot) {
  __shared__ __align__(16) unsigned short As[128 * 64];
  __shared__ __align__(16) unsigned short Bs[128 * 64];
  int z = blockIdx.z;
  float* C = Cp + (size_t)z * M * N;
  int kbeg = z * Kpart;
  int row0 = blockIdx.y * 128, col0 = blockIdx.x * 128;
  int t = threadIdx.x;
  int w = t >> 6, lane = t & 63, quad = lane >> 4, l16 = lane & 15;
  int wm = w & 1, wn = w >> 1;
  int srow = lane >> 3;            // 0..7 within one 1KB instr
  int scol = (lane & 7) * 8;       // element column

  f32x4 acc[4][4];
#pragma unroll
  for (int i = 0; i < 4; ++i)
#pragma unroll
    for (int j = 0; j < 4; ++j) acc[i][j] = (f32x4){0.f, 0.f, 0.f, 0.f};

  for (int k0 = kbeg; k0 < kbeg + Kpart; k0 += 64) {
#pragma unroll
    for (int j = 0; j < 4; ++j) {
      int r = w * 32 + j * 8 + srow;
      gload_lds16(A + (size_t)(row0 + r) * Ktot + k0 + scol, &As[(w * 32 + j * 8) * 64]);
      gload_lds16(BT + (size_t)(col0 + r) * Ktot + k0 + scol, &Bs[(w * 32 + j * 8) * 64]);
    }
    __syncthreads();
#pragma unroll
    for (int ks = 0; ks < 2; ++ks) {
      bf16x8 af[4], bfr[4];
#pragma unroll
      for (int i = 0; i < 4; ++i)
        af[i] = *reinterpret_cast<const bf16x8*>(&As[(wm * 64 + i * 16 + l16) * 64 + ks * 32 + quad * 8]);
#pragma unroll
      for (int i = 0; i < 4; ++i)
        bfr[i] = *reinterpret_cast<const bf16x8*>(&Bs[(wn * 64 + i * 16 + l16) * 64 + ks * 32 + quad * 8]);
#pragma unroll
      for (int am = 0; am < 4; ++am)
#pragma unroll
        for (int bn = 0; bn < 4; ++bn)
          acc[am][bn] = __builtin_amdgcn_mfma_f32_16x16x32_bf16(af[am], bfr[bn], acc[am][bn], 0, 0, 0);
    }
    __syncthreads();
  }
#pragma unroll
  for (int am = 0; am < 4; ++am)
#pragma unroll
    for (int bn = 0; bn < 4; ++bn) {
      int row = row0 + wm * 64 + am * 16 + quad * 4;
      float* Cptr = C + (size_t)row * N + col0 + wn * 64 + bn * 16 + l16;
#pragma unroll
      for (int rg = 0; rg < 4; ++rg) Cptr[(size_t)rg * N] = acc[am][bn][rg];
    }
}

// ---------------- RMSNorm + RoPE (reads the two split-K partials) ----------------
__global__ __launch_bounds__(256) void norm_rope_kernel(const float* __restrict__ qkv,
                                                        const float* __restrict__ q_scale,
                                                        const float* __restrict__ k_scale,
                                                        unsigned short* __restrict__ qb,
                                                        unsigned short* __restrict__ kbuf) {
  const size_t HALFQ = (size_t)MROWS * NQKV;
  int wid = (blockIdx.x * 256 + threadIdx.x) >> 6;
  int lane = threadIdx.x & 63;
  int r = wid / 20, hh = wid % 20;         // r = b*S + s
  int b = r >> 11, s = r & 2047;
  size_t sidx;
  const float* scale;
  unsigned short* dst;
  float post;
  if (hh < 16) {
    sidx = (size_t)r * NQKV + hh * 64;
    scale = q_scale;
    dst = qb + ((size_t)(b * NH + hh) * S_LEN + s) * HD;
    post = 1.0f;
  } else {
    int kvh = hh - 16;
    sidx = (size_t)r * NQKV + 1024 + kvh * 64;
    scale = k_scale;
    dst = kbuf + ((size_t)(b * NKV + kvh) * S_LEN + s) * HD;
    post = 0.125f * 1.44269504088896f;   // fold score scale + log2(e) into k
  }
  float v = qkv[sidx + lane] + qkv[sidx + HALFQ + lane];
  float ss = v * v;
#pragma unroll
  for (int m = 1; m < 64; m <<= 1) ss += __shfl_xor(ss, m, 64);
  float rms = sqrtf(ss * (1.0f / 64.0f) + 1e-5f);
  float nv = v / rms * scale[lane];
  int dh = lane & 31;
  float inv = exp2f((float)dh * (-13.2877123795495f / 32.0f));  // 10000^(-dh/32)
  float f = (float)s * inv;
  float c = cosf(f), sn = sinf(f);
  float partner = __shfl_xor(nv, 32, 64);
  float outv = (lane < 32) ? (nv * c - partner * sn) : (partner * sn + nv * c);
  dst[lane] = f2bf(outv * post);
}

// ------- V: (s,d) fp32 slice of qkv partials -> vT (B,NKV,64,S) bf16 -------
__global__ __launch_bounds__(256) void v_transpose_kernel(const float* __restrict__ qkv,
                                                          unsigned short* __restrict__ vt) {
  const size_t HALFQ = (size_t)MROWS * NQKV;
  __shared__ float tile[64][65];
  int bkv = blockIdx.x >> 5;              // 0..7 = b*NKV+kvh
  int b = bkv >> 2, kvh = bkv & 3;
  int s0 = (blockIdx.x & 31) * 64;
  int t = threadIdx.x;
  int sl = t >> 2, ds = (t & 3) * 16;
  const float* src = qkv + (size_t)(b * S_LEN + s0 + sl) * NQKV + 1280 + kvh * 64 + ds;
#pragma unroll
  for (int k = 0; k < 4; ++k) {
    float4 v = *reinterpret_cast<const float4*>(src + 4 * k);
    float4 v2 = *reinterpret_cast<const float4*>(src + HALFQ + 4 * k);
    tile[sl][ds + 4 * k + 0] = v.x + v2.x;
    tile[sl][ds + 4 * k + 1] = v.y + v2.y;
    tile[sl][ds + 4 * k + 2] = v.z + v2.z;
    tile[sl][ds + 4 * k + 3] = v.w + v2.w;
  }
  __syncthreads();
  int d = t >> 2, ssg = (t & 3) * 16;
  bf16x8 v0, v1;
#pragma unroll
  for (int i = 0; i < 8; ++i) v0[i] = (short)f2bf(tile[ssg + i][d]);
#pragma unroll
  for (int i = 0; i < 8; ++i) v1[i] = (short)f2bf(tile[ssg + 8 + i][d]);
  unsigned short* dst = vt + ((size_t)bkv * 64 + d) * S_LEN + s0 + ssg;
  *reinterpret_cast<bf16x8*>(dst) = v0;
  *reinterpret_cast<bf16x8*>(dst + 8) = v1;
}

// ------- causal flash attention: GQA-shared blocks -------
// 4 waves/block = the 4 q-heads of one kv group, same q-tile: identical K/V
// addresses per iteration -> one L1 fill serves 4 waves. Wave-private P LDS,
// no barriers, no shuffles. Fixed-max exp2 softmax; l via ones-row MFMA.
__global__ __launch_bounds__(256) void attn_kernel(const unsigned short* __restrict__ qb,
                                                   const unsigned short* __restrict__ kbuf,
                                                   const unsigned short* __restrict__ vt,
                                                   unsigned short* __restrict__ ctx) {
  __shared__ __align__(16) unsigned short PT[4][2][16][72];
  int g = blockIdx.x >> 3;                 // 0..63 q-tile slot
  int bkv = blockIdx.x & 7;                // b*NKV + kvh
  int t32 = (g < 32) ? (63 - g) : (g - 32);  // complementary pairing: CU's two blocks sum const
  int b = bkv >> 2, kvh = bkv & 3;
  int w = threadIdx.x >> 6;                // head within kv group
  int h = kvh * 4 + w;
  int lane = threadIdx.x & 63;
  int quad = lane >> 4, l16 = lane & 15;
  int qa = t32 * 32 + l16;                 // q-group a; group b = qa + 16
  const unsigned short* Q = qb + (size_t)(b * NH + h) * S_LEN * HD;
  const unsigned short* Kh = kbuf + (size_t)(b * NKV + kvh) * S_LEN * HD;
  const unsigned short* Vh = vt + (size_t)(b * NKV + kvh) * HD * S_LEN;

  bf16x8 bqa0 = *reinterpret_cast<const bf16x8*>(Q + (size_t)qa * HD + quad * 8);
  bf16x8 bqa1 = *reinterpret_cast<const bf16x8*>(Q + (size_t)qa * HD + 32 + quad * 8);
  bf16x8 bqb0 = *reinterpret_cast<const bf16x8*>(Q + (size_t)(qa + 16) * HD + quad * 8);
  bf16x8 bqb1 = *reinterpret_cast<const bf16x8*>(Q + (size_t)(qa + 16) * HD + 32 + quad * 8);

  bf16x8 ones;
#pragma unroll
  for (int i = 0; i < 8; ++i) ones[i] = (short)0x3F80;   // bf16 1.0

  f32x4 ot[2][4];
#pragma unroll
  for (int gq = 0; gq < 2; ++gq)
#pragma unroll
    for (int i = 0; i < 4; ++i) ot[gq][i] = (f32x4){0.f, 0.f, 0.f, 0.f};
  f32x4 ol[2] = {(f32x4){0.f, 0.f, 0.f, 0.f}, (f32x4){0.f, 0.f, 0.f, 0.f}};

  int nkb = (t32 >> 1) + 1;

  bf16x8 kc0[4], kc1[4];
#pragma unroll
  for (int km = 0; km < 4; ++km) {
    const unsigned short* kp = Kh + (size_t)(km * 16 + l16) * HD;
    kc0[km] = *reinterpret_cast<const bf16x8*>(kp + quad * 8);
    kc1[km] = *reinterpret_cast<const bf16x8*>(kp + 32 + quad * 8);
  }

  for (int kbi = 0; kbi < nkb; ++kbi) {
    bool last = (kbi == nkb - 1);
    int kbase = kbi << 6;
    f32x4 sa[4], sb[4];
#pragma unroll
    for (int km = 0; km < 4; ++km) {
      f32x4 s = {0.f, 0.f, 0.f, 0.f};
      s = __builtin_amdgcn_mfma_f32_16x16x32_bf16(kc0[km], bqa0, s, 0, 0, 0);
      s = __builtin_amdgcn_mfma_f32_16x16x32_bf16(kc1[km], bqa1, s, 0, 0, 0);
      sa[km] = s;
      f32x4 s2 = {0.f, 0.f, 0.f, 0.f};
      s2 = __builtin_amdgcn_mfma_f32_16x16x32_bf16(kc0[km], bqb0, s2, 0, 0, 0);
      s2 = __builtin_amdgcn_mfma_f32_16x16x32_bf16(kc1[km], bqb1, s2, 0, 0, 0);
      sb[km] = s2;
    }
    // V loads (same addresses across waves -> L1 broadcast)
    bf16x8 va0[4], va1[4];
#pragma unroll
    for (int dm = 0; dm < 4; ++dm) {
      const unsigned short* vp = Vh + (size_t)(dm * 16 + l16) * S_LEN + kbase;
      va0[dm] = *reinterpret_cast<const bf16x8*>(vp + quad * 8);
      va1[dm] = *reinterpret_cast<const bf16x8*>(vp + 32 + quad * 8);
    }
    if (!last) {
      const unsigned short* kp = Kh + (size_t)(kbase + 64 + l16) * HD;
#pragma unroll
      for (int km = 0; km < 4; ++km) {
        kc0[km] = *reinterpret_cast<const bf16x8*>(kp + (size_t)(km * 16) * HD + quad * 8);
        kc1[km] = *reinterpret_cast<const bf16x8*>(kp + (size_t)(km * 16) * HD + 32 + quad * 8);
      }
    } else {
#pragma unroll
      for (int km = 0; km < 4; ++km)
#pragma unroll
        for (int rg = 0; rg < 4; ++rg) {
          int key = kbase + km * 16 + quad * 4 + rg;
          if (key > qa) sa[km][rg] = -1e30f;
          if (key > qa + 16) sb[km][rg] = -1e30f;
        }
    }
    // p = exp2(s); one v_perm per pair packs truncated bf16
#pragma unroll
    for (int km = 0; km < 4; ++km) {
      float a0 = exp2f(sa[km][0]), a1 = exp2f(sa[km][1]);
      float a2 = exp2f(sa[km][2]), a3 = exp2f(sa[km][3]);
      uint2 pw;
      pw.x = __builtin_amdgcn_perm(__float_as_uint(a1), __float_as_uint(a0), 0x07060302);
      pw.y = __builtin_amdgcn_perm(__float_as_uint(a3), __float_as_uint(a2), 0x07060302);
      *reinterpret_cast<uint2*>(&PT[w][0][l16][km * 16 + quad * 4]) = pw;
      float b0 = exp2f(sb[km][0]), b1 = exp2f(sb[km][1]);
      float b2 = exp2f(sb[km][2]), b3 = exp2f(sb[km][3]);
      uint2 qw;
      qw.x = __builtin_amdgcn_perm(__float_as_uint(b1), __float_as_uint(b0), 0x07060302);
      qw.y = __builtin_amdgcn_perm(__float_as_uint(b3), __float_as_uint(b2), 0x07060302);
      *reinterpret_cast<uint2*>(&PT[w][1][l16][km * 16 + quad * 4]) = qw;
    }
    // wave-private LDS roundtrip: C-layout -> B-operand layout
    bf16x8 pa0 = *reinterpret_cast<const bf16x8*>(&PT[w][0][l16][quad * 8]);
    bf16x8 pa1 = *reinterpret_cast<const bf16x8*>(&PT[w][0][l16][32 + quad * 8]);
    bf16x8 pb0 = *reinterpret_cast<const bf16x8*>(&PT[w][1][l16][quad * 8]);
    bf16x8 pb1 = *reinterpret_cast<const bf16x8*>(&PT[w][1][l16][32 + quad * 8]);
    ol[0] = __builtin_amdgcn_mfma_f32_16x16x32_bf16(ones, pa0, ol[0], 0, 0, 0);
    ol[0] = __builtin_amdgcn_mfma_f32_16x16x32_bf16(ones, pa1, ol[0], 0, 0, 0);
    ol[1] = __builtin_amdgcn_mfma_f32_16x16x32_bf16(ones, pb0, ol[1], 0, 0, 0);
    ol[1] = __builtin_amdgcn_mfma_f32_16x16x32_bf16(ones, pb1, ol[1], 0, 0, 0);
#pragma unroll
    for (int dm = 0; dm < 4; ++dm) {
      ot[0][dm] = __builtin_amdgcn_mfma_f32_16x16x32_bf16(va0[dm], pa0, ot[0][dm], 0, 0, 0);
      ot[0][dm] = __builtin_amdgcn_mfma_f32_16x16x32_bf16(va1[dm], pa1, ot[0][dm], 0, 0, 0);
      ot[1][dm] = __builtin_amdgcn_mfma_f32_16x16x32_bf16(va0[dm], pb0, ot[1][dm], 0, 0, 0);
      ot[1][dm] = __builtin_amdgcn_mfma_f32_16x16x32_bf16(va1[dm], pb1, ot[1][dm], 0, 0, 0);
    }
  }

#pragma unroll
  for (int gq = 0; gq < 2; ++gq) {
    float inv_l = 1.0f / ol[gq][0];
    size_t base = ((size_t)(b * S_LEN) + qa + gq * 16) * DM + h * HD;
#pragma unroll
    for (int dm = 0; dm < 4; ++dm) {
      s16x4 pv;
#pragma unroll
      for (int rg = 0; rg < 4; ++rg) pv[rg] = (short)f2bf(ot[gq][dm][rg] * inv_l);
      *reinterpret_cast<s16x4*>(ctx + base + dm * 16 + quad * 4) = pv;
    }
  }
}

// ---------------- out = partial0 + partial1 ----------------
__global__ __launch_bounds__(256) void add_out_kernel(const float* __restrict__ a,
                                                      const float* __restrict__ b,
                                                      float* __restrict__ o, int n) {
  int i = (blockIdx.x * 256 + threadIdx.x) * 4;
  if (i < n) {
    float4 x = *reinterpret_cast<const float4*>(a + i);
    float4 y = *reinterpret_cast<const float4*>(b + i);
    float4 r = {x.x + y.x, x.y + y.y, x.z + y.z, x.w + y.w};
    *reinterpret_cast<float4*>(o + i) = r;
  }
}

// ---------------- launch ----------------
extern "C" void kernel_launch(void* const* d_in, const int* in_sizes, int n_in,
                              void* d_out, int out_size, void* d_ws, size_t ws_size,
                              hipStream_t stream) {
  const float* x = (const float*)d_in[0];
  const float* Wq = (const float*)d_in[1];
  const float* Wkv = (const float*)d_in[2];
  const float* Wo = (const float*)d_in[3];
  const float* q_scale = (const float*)d_in[4];
  const float* k_scale = (const float*)d_in[5];
  float* out = (float*)d_out;

  char* ws = (char*)d_ws;
  size_t off = 0;
  auto alloc = [&](size_t bytes) {
    void* p = ws + off;
    off += (bytes + 255) & ~(size_t)255;
    return p;
  };
  unsigned short* xb = (unsigned short*)alloc((size_t)MROWS * DM * 2);
  unsigned short* wt1 = (unsigned short*)alloc((size_t)NQKV * DM * 2);   // [Wq^T ; Wkv^T]
  unsigned short* wot = (unsigned short*)alloc((size_t)DM * DM * 2);
  float* qkvp = (float*)alloc(2 * (size_t)MROWS * NQKV * 4);             // split-K partials
  unsigned short* qb = (unsigned short*)alloc((size_t)BATCH * NH * S_LEN * HD * 2);
  unsigned short* kbuf = (unsigned short*)alloc((size_t)BATCH * NKV * S_LEN * HD * 2);
  unsigned short* vt = (unsigned short*)alloc((size_t)BATCH * NKV * HD * S_LEN * 2);
  unsigned short* ctx = (unsigned short*)alloc((size_t)MROWS * DM * 2);
  float* outp = (float*)alloc(2 * (size_t)MROWS * DM * 4);               // split-K partials

  cvt_x_kernel<<<(MROWS * DM) / 1024, 256, 0, stream>>>(x, xb, MROWS * DM);
  transpose_cvt_kernel<<<dim3(16, 16), 256, 0, stream>>>(Wq, wt1, 1024, 1024);
  transpose_cvt_kernel<<<dim3(8, 16), 256, 0, stream>>>(Wkv, wt1 + 1024 * 1024, 1024, 512);
  transpose_cvt_kernel<<<dim3(16, 16), 256, 0, stream>>>(Wo, wot, 1024, 1024);

  gemm_bt_splitk<<<dim3(NQKV / 128, MROWS / 128, 2), 256, 0, stream>>>(xb, wt1, qkvp,
                                                                       MROWS, NQKV, 512, DM);

  norm_rope_kernel<<<(MROWS * 20) / 4, 256, 0, stream>>>(qkvp, q_scale, k_scale, qb, kbuf);
  v_transpose_kernel<<<256, 256, 0, stream>>>(qkvp, vt);

  attn_kernel<<<BATCH * NKV * (S_LEN / 32), 256, 0, stream>>>(qb, kbuf, vt, ctx);

  gemm_bt_splitk<<<dim3(DM / 128, MROWS / 128, 2), 256, 0, stream>>>(ctx, wot, outp,
                                                                     MROWS, DM, 512, DM);
  add_out_kernel<<<(MROWS * DM) / 1024, 256, 0, stream>>>(outp, outp + (size_t)MROWS * DM,
                                                          out, MROWS * DM);
}

// Round 6
// 227.988 us; speedup vs baseline: 1.0554x; 1.0554x over previous
//
#include <hip/hip_runtime.h>

#define S_LEN 2048
#define BATCH 2
#define DM    1024
#define NH    16
#define NKV   4
#define HD    64
#define MROWS (BATCH * S_LEN)   // 4096
#define NQKV  1536              // 1024 q + 512 kv

typedef __attribute__((ext_vector_type(8))) short bf16x8;
typedef __attribute__((ext_vector_type(4))) short s16x4;
typedef __attribute__((ext_vector_type(4))) float f32x4;

__device__ __forceinline__ unsigned short f2bf(float f) {
  unsigned int u = __float_as_uint(f);
  u += 0x7FFF + ((u >> 16) & 1);   // RNE
  return (unsigned short)(u >> 16);
}

__device__ __forceinline__ void gload_lds16(const unsigned short* g, unsigned short* l) {
  __builtin_amdgcn_global_load_lds((const __attribute__((address_space(1))) void*)g,
                                   (__attribute__((address_space(3))) void*)l, 16, 0, 0);
}

// ---------------- x -> bf16 ----------------
__global__ __launch_bounds__(256) void cvt_x_kernel(const float* __restrict__ x,
                                                    unsigned short* __restrict__ xb, int n) {
  int i = (blockIdx.x * 256 + threadIdx.x) * 4;
  if (i < n) {
    float4 v = *reinterpret_cast<const float4*>(x + i);
    xb[i + 0] = f2bf(v.x);
    xb[i + 1] = f2bf(v.y);
    xb[i + 2] = f2bf(v.z);
    xb[i + 3] = f2bf(v.w);
  }
}

// ---------------- W (RxC fp32) -> W^T (CxR bf16) ----------------
__global__ __launch_bounds__(256) void transpose_cvt_kernel(const float* __restrict__ in,
                                                            unsigned short* __restrict__ out,
                                                            int R, int C) {
  __shared__ float tile[64][65];
  int r0 = blockIdx.y * 64, c0 = blockIdx.x * 64;
  int t = threadIdx.x;
  int rl = t >> 2, cs = (t & 3) * 16;
#pragma unroll
  for (int k = 0; k < 4; ++k) {
    float4 v = *reinterpret_cast<const float4*>(in + (size_t)(r0 + rl) * C + c0 + cs + 4 * k);
    tile[rl][cs + 4 * k + 0] = v.x;
    tile[rl][cs + 4 * k + 1] = v.y;
    tile[rl][cs + 4 * k + 2] = v.z;
    tile[rl][cs + 4 * k + 3] = v.w;
  }
  __syncthreads();
  int cl = t >> 2, rs = (t & 3) * 16;
  bf16x8 v0, v1;
#pragma unroll
  for (int i = 0; i < 8; ++i) v0[i] = (short)f2bf(tile[rs + i][cl]);
#pragma unroll
  for (int i = 0; i < 8; ++i) v1[i] = (short)f2bf(tile[rs + 8 + i][cl]);
  unsigned short* dst = out + (size_t)(c0 + cl) * R + r0 + rs;
  *reinterpret_cast<bf16x8*>(dst) = v0;
  *reinterpret_cast<bf16x8*>(dst + 8) = v1;
}

// ------- bf16 GEMM, split-K(2), m97 structure: global_load_lds staging -------
__global__ __launch_bounds__(256) void gemm_bt_splitk(const unsigned short* __restrict__ A,
                                                      const unsigned short* __restrict__ BT,
                                                      float* __restrict__ Cp,
                                                      int M, int N, int Kpart, int Ktot) {
  __shared__ __align__(16) unsigned short As[128 * 64];
  __shared__ __align__(16) unsigned short Bs[128 * 64];
  int z = blockIdx.z;
  float* C = Cp + (size_t)z * M * N;
  int kbeg = z * Kpart;
  int row0 = blockIdx.y * 128, col0 = blockIdx.x * 128;
  int t = threadIdx.x;
  int w = t >> 6, lane = t & 63, quad = lane >> 4, l16 = lane & 15;
  int wm = w & 1, wn = w >> 1;
  int srow = lane >> 3;            // 0..7 within one 1KB instr
  int scol = (lane & 7) * 8;       // element column

  f32x4 acc[4][4];
#pragma unroll
  for (int i = 0; i < 4; ++i)
#pragma unroll
    for (int j = 0; j < 4; ++j) acc[i][j] = (f32x4){0.f, 0.f, 0.f, 0.f};

  for (int k0 = kbeg; k0 < kbeg + Kpart; k0 += 64) {
#pragma unroll
    for (int j = 0; j < 4; ++j) {
      int r = w * 32 + j * 8 + srow;
      gload_lds16(A + (size_t)(row0 + r) * Ktot + k0 + scol, &As[(w * 32 + j * 8) * 64]);
      gload_lds16(BT + (size_t)(col0 + r) * Ktot + k0 + scol, &Bs[(w * 32 + j * 8) * 64]);
    }
    __syncthreads();
#pragma unroll
    for (int ks = 0; ks < 2; ++ks) {
      bf16x8 af[4], bfr[4];
#pragma unroll
      for (int i = 0; i < 4; ++i)
        af[i] = *reinterpret_cast<const bf16x8*>(&As[(wm * 64 + i * 16 + l16) * 64 + ks * 32 + quad * 8]);
#pragma unroll
      for (int i = 0; i < 4; ++i)
        bfr[i] = *reinterpret_cast<const bf16x8*>(&Bs[(wn * 64 + i * 16 + l16) * 64 + ks * 32 + quad * 8]);
#pragma unroll
      for (int am = 0; am < 4; ++am)
#pragma unroll
        for (int bn = 0; bn < 4; ++bn)
          acc[am][bn] = __builtin_amdgcn_mfma_f32_16x16x32_bf16(af[am], bfr[bn], acc[am][bn], 0, 0, 0);
    }
    __syncthreads();
  }
#pragma unroll
  for (int am = 0; am < 4; ++am)
#pragma unroll
    for (int bn = 0; bn < 4; ++bn) {
      int row = row0 + wm * 64 + am * 16 + quad * 4;
      float* Cptr = C + (size_t)row * N + col0 + wn * 64 + bn * 16 + l16;
#pragma unroll
      for (int rg = 0; rg < 4; ++rg) Cptr[(size_t)rg * N] = acc[am][bn][rg];
    }
}

// ---------------- RMSNorm + RoPE (reads the two split-K partials) ----------------
__global__ __launch_bounds__(256) void norm_rope_kernel(const float* __restrict__ qkv,
                                                        const float* __restrict__ q_scale,
                                                        const float* __restrict__ k_scale,
                                                        unsigned short* __restrict__ qb,
                                                        unsigned short* __restrict__ kbuf) {
  const size_t HALFQ = (size_t)MROWS * NQKV;
  int wid = (blockIdx.x * 256 + threadIdx.x) >> 6;
  int lane = threadIdx.x & 63;
  int r = wid / 20, hh = wid % 20;         // r = b*S + s
  int b = r >> 11, s = r & 2047;
  size_t sidx;
  const float* scale;
  unsigned short* dst;
  float post;
  if (hh < 16) {
    sidx = (size_t)r * NQKV + hh * 64;
    scale = q_scale;
    dst = qb + ((size_t)(b * NH + hh) * S_LEN + s) * HD;
    post = 1.0f;
  } else {
    int kvh = hh - 16;
    sidx = (size_t)r * NQKV + 1024 + kvh * 64;
    scale = k_scale;
    dst = kbuf + ((size_t)(b * NKV + kvh) * S_LEN + s) * HD;
    post = 0.125f * 1.44269504088896f;   // fold score scale + log2(e) into k
  }
  float v = qkv[sidx + lane] + qkv[sidx + HALFQ + lane];
  float ss = v * v;
#pragma unroll
  for (int m = 1; m < 64; m <<= 1) ss += __shfl_xor(ss, m, 64);
  float rms = sqrtf(ss * (1.0f / 64.0f) + 1e-5f);
  float nv = v / rms * scale[lane];
  int dh = lane & 31;
  float inv = exp2f((float)dh * (-13.2877123795495f / 32.0f));  // 10000^(-dh/32)
  float f = (float)s * inv;
  float c = cosf(f), sn = sinf(f);
  float partner = __shfl_xor(nv, 32, 64);
  float outv = (lane < 32) ? (nv * c - partner * sn) : (partner * sn + nv * c);
  dst[lane] = f2bf(outv * post);
}

// ------- V: (s,d) fp32 slice of qkv partials -> vT (B,NKV,64,S) bf16 -------
__global__ __launch_bounds__(256) void v_transpose_kernel(const float* __restrict__ qkv,
                                                          unsigned short* __restrict__ vt) {
  const size_t HALFQ = (size_t)MROWS * NQKV;
  __shared__ float tile[64][65];
  int bkv = blockIdx.x >> 5;              // 0..7 = b*NKV+kvh
  int b = bkv >> 2, kvh = bkv & 3;
  int s0 = (blockIdx.x & 31) * 64;
  int t = threadIdx.x;
  int sl = t >> 2, ds = (t & 3) * 16;
  const float* src = qkv + (size_t)(b * S_LEN + s0 + sl) * NQKV + 1280 + kvh * 64 + ds;
#pragma unroll
  for (int k = 0; k < 4; ++k) {
    float4 v = *reinterpret_cast<const float4*>(src + 4 * k);
    float4 v2 = *reinterpret_cast<const float4*>(src + HALFQ + 4 * k);
    tile[sl][ds + 4 * k + 0] = v.x + v2.x;
    tile[sl][ds + 4 * k + 1] = v.y + v2.y;
    tile[sl][ds + 4 * k + 2] = v.z + v2.z;
    tile[sl][ds + 4 * k + 3] = v.w + v2.w;
  }
  __syncthreads();
  int d = t >> 2, ssg = (t & 3) * 16;
  bf16x8 v0, v1;
#pragma unroll
  for (int i = 0; i < 8; ++i) v0[i] = (short)f2bf(tile[ssg + i][d]);
#pragma unroll
  for (int i = 0; i < 8; ++i) v1[i] = (short)f2bf(tile[ssg + 8 + i][d]);
  unsigned short* dst = vt + ((size_t)bkv * 64 + d) * S_LEN + s0 + ssg;
  *reinterpret_cast<bf16x8*>(dst) = v0;
  *reinterpret_cast<bf16x8*>(dst + 8) = v1;
}

// ------- causal flash attention: GQA-shared blocks, register-pipelined -------
// 4 waves/block = 4 q-heads of one kv group (same K/V addresses -> L1 broadcast).
// K(i+1)/V(i+1) prefetched into rotating register buffers at the TOP of iter i:
// liveness across the back-edge forces resident operands + early load issue.
// __launch_bounds__(256,1) unlocks the VGPR budget (~200 regs, 2 waves/SIMD).
__global__ __launch_bounds__(256, 1) void attn_kernel(const unsigned short* __restrict__ qb,
                                                      const unsigned short* __restrict__ kbuf,
                                                      const unsigned short* __restrict__ vt,
                                                      unsigned short* __restrict__ ctx) {
  __shared__ __align__(16) unsigned short PT[4][2][16][72];
  int g = blockIdx.x >> 3;                 // 0..63 q-tile slot
  int bkv = blockIdx.x & 7;                // b*NKV + kvh
  int t32 = (g < 32) ? (63 - g) : (g - 32);  // complementary pairing
  int b = bkv >> 2, kvh = bkv & 3;
  int w = threadIdx.x >> 6;                // head within kv group
  int h = kvh * 4 + w;
  int lane = threadIdx.x & 63;
  int quad = lane >> 4, l16 = lane & 15;
  int qa = t32 * 32 + l16;                 // q-group a; group b = qa + 16
  const unsigned short* Q = qb + (size_t)(b * NH + h) * S_LEN * HD;
  const unsigned short* Kh = kbuf + (size_t)(b * NKV + kvh) * S_LEN * HD;
  const unsigned short* Vh = vt + (size_t)(b * NKV + kvh) * HD * S_LEN;

  bf16x8 bqa0 = *reinterpret_cast<const bf16x8*>(Q + (size_t)qa * HD + quad * 8);
  bf16x8 bqa1 = *reinterpret_cast<const bf16x8*>(Q + (size_t)qa * HD + 32 + quad * 8);
  bf16x8 bqb0 = *reinterpret_cast<const bf16x8*>(Q + (size_t)(qa + 16) * HD + quad * 8);
  bf16x8 bqb1 = *reinterpret_cast<const bf16x8*>(Q + (size_t)(qa + 16) * HD + 32 + quad * 8);

  bf16x8 ones;
#pragma unroll
  for (int i = 0; i < 8; ++i) ones[i] = (short)0x3F80;   // bf16 1.0

  f32x4 ot[2][4];
#pragma unroll
  for (int gq = 0; gq < 2; ++gq)
#pragma unroll
    for (int i = 0; i < 4; ++i) ot[gq][i] = (f32x4){0.f, 0.f, 0.f, 0.f};
  f32x4 ol[2] = {(f32x4){0.f, 0.f, 0.f, 0.f}, (f32x4){0.f, 0.f, 0.f, 0.f}};

  int nkb = (t32 >> 1) + 1;

  // current K/V tile in registers (prefetched one iteration ahead)
  bf16x8 kc0[4], kc1[4], vc0[4], vc1[4];
#pragma unroll
  for (int km = 0; km < 4; ++km) {
    const unsigned short* kp = Kh + (size_t)(km * 16 + l16) * HD;
    kc0[km] = *reinterpret_cast<const bf16x8*>(kp + quad * 8);
    kc1[km] = *reinterpret_cast<const bf16x8*>(kp + 32 + quad * 8);
    const unsigned short* vp = Vh + (size_t)(km * 16 + l16) * S_LEN;
    vc0[km] = *reinterpret_cast<const bf16x8*>(vp + quad * 8);
    vc1[km] = *reinterpret_cast<const bf16x8*>(vp + 32 + quad * 8);
  }

  for (int kbi = 0; kbi < nkb; ++kbi) {
    bool last = (kbi == nkb - 1);
    int kbase = kbi << 6;
    // prefetch next tile FIRST: a full iteration of compute hides the latency
    bf16x8 kn0[4], kn1[4], vn0[4], vn1[4];
    if (!last) {
      const unsigned short* kp = Kh + (size_t)(kbase + 64 + l16) * HD;
      const unsigned short* vp = Vh + (size_t)l16 * S_LEN + kbase + 64;
#pragma unroll
      for (int km = 0; km < 4; ++km) {
        kn0[km] = *reinterpret_cast<const bf16x8*>(kp + (size_t)(km * 16) * HD + quad * 8);
        kn1[km] = *reinterpret_cast<const bf16x8*>(kp + (size_t)(km * 16) * HD + 32 + quad * 8);
        vn0[km] = *reinterpret_cast<const bf16x8*>(vp + (size_t)(km * 16) * S_LEN + quad * 8);
        vn1[km] = *reinterpret_cast<const bf16x8*>(vp + (size_t)(km * 16) * S_LEN + 32 + quad * 8);
      }
    }
    // QK^T from current (register-resident) K
    f32x4 sa[4], sb[4];
#pragma unroll
    for (int km = 0; km < 4; ++km) {
      f32x4 s = {0.f, 0.f, 0.f, 0.f};
      s = __builtin_amdgcn_mfma_f32_16x16x32_bf16(kc0[km], bqa0, s, 0, 0, 0);
      s = __builtin_amdgcn_mfma_f32_16x16x32_bf16(kc1[km], bqa1, s, 0, 0, 0);
      sa[km] = s;
      f32x4 s2 = {0.f, 0.f, 0.f, 0.f};
      s2 = __builtin_amdgcn_mfma_f32_16x16x32_bf16(kc0[km], bqb0, s2, 0, 0, 0);
      s2 = __builtin_amdgcn_mfma_f32_16x16x32_bf16(kc1[km], bqb1, s2, 0, 0, 0);
      sb[km] = s2;
    }
    if (last) {
#pragma unroll
      for (int km = 0; km < 4; ++km)
#pragma unroll
        for (int rg = 0; rg < 4; ++rg) {
          int key = kbase + km * 16 + quad * 4 + rg;
          if (key > qa) sa[km][rg] = -1e30f;
          if (key > qa + 16) sb[km][rg] = -1e30f;
        }
    }
    // p = exp2(s); one v_perm per pair packs truncated bf16
#pragma unroll
    for (int km = 0; km < 4; ++km) {
      float a0 = exp2f(sa[km][0]), a1 = exp2f(sa[km][1]);
      float a2 = exp2f(sa[km][2]), a3 = exp2f(sa[km][3]);
      uint2 pw;
      pw.x = __builtin_amdgcn_perm(__float_as_uint(a1), __float_as_uint(a0), 0x07060302);
      pw.y = __builtin_amdgcn_perm(__float_as_uint(a3), __float_as_uint(a2), 0x07060302);
      *reinterpret_cast<uint2*>(&PT[w][0][l16][km * 16 + quad * 4]) = pw;
      float b0 = exp2f(sb[km][0]), b1 = exp2f(sb[km][1]);
      float b2 = exp2f(sb[km][2]), b3 = exp2f(sb[km][3]);
      uint2 qw;
      qw.x = __builtin_amdgcn_perm(__float_as_uint(b1), __float_as_uint(b0), 0x07060302);
      qw.y = __builtin_amdgcn_perm(__float_as_uint(b3), __float_as_uint(b2), 0x07060302);
      *reinterpret_cast<uint2*>(&PT[w][1][l16][km * 16 + quad * 4]) = qw;
    }
    // wave-private LDS roundtrip: C-layout -> B-operand layout
    bf16x8 pa0 = *reinterpret_cast<const bf16x8*>(&PT[w][0][l16][quad * 8]);
    bf16x8 pa1 = *reinterpret_cast<const bf16x8*>(&PT[w][0][l16][32 + quad * 8]);
    bf16x8 pb0 = *reinterpret_cast<const bf16x8*>(&PT[w][1][l16][quad * 8]);
    bf16x8 pb1 = *reinterpret_cast<const bf16x8*>(&PT[w][1][l16][32 + quad * 8]);
    ol[0] = __builtin_amdgcn_mfma_f32_16x16x32_bf16(ones, pa0, ol[0], 0, 0, 0);
    ol[0] = __builtin_amdgcn_mfma_f32_16x16x32_bf16(ones, pa1, ol[0], 0, 0, 0);
    ol[1] = __builtin_amdgcn_mfma_f32_16x16x32_bf16(ones, pb0, ol[1], 0, 0, 0);
    ol[1] = __builtin_amdgcn_mfma_f32_16x16x32_bf16(ones, pb1, ol[1], 0, 0, 0);
#pragma unroll
    for (int dm = 0; dm < 4; ++dm) {
      ot[0][dm] = __builtin_amdgcn_mfma_f32_16x16x32_bf16(vc0[dm], pa0, ot[0][dm], 0, 0, 0);
      ot[0][dm] = __builtin_amdgcn_mfma_f32_16x16x32_bf16(vc1[dm], pa1, ot[0][dm], 0, 0, 0);
      ot[1][dm] = __builtin_amdgcn_mfma_f32_16x16x32_bf16(vc0[dm], pb0, ot[1][dm], 0, 0, 0);
      ot[1][dm] = __builtin_amdgcn_mfma_f32_16x16x32_bf16(vc1[dm], pb1, ot[1][dm], 0, 0, 0);
    }
    // rotate prefetch buffers
    if (!last) {
#pragma unroll
      for (int km = 0; km < 4; ++km) {
        kc0[km] = kn0[km]; kc1[km] = kn1[km];
        vc0[km] = vn0[km]; vc1[km] = vn1[km];
      }
    }
  }

#pragma unroll
  for (int gq = 0; gq < 2; ++gq) {
    float inv_l = 1.0f / ol[gq][0];
    size_t base = ((size_t)(b * S_LEN) + qa + gq * 16) * DM + h * HD;
#pragma unroll
    for (int dm = 0; dm < 4; ++dm) {
      s16x4 pv;
#pragma unroll
      for (int rg = 0; rg < 4; ++rg) pv[rg] = (short)f2bf(ot[gq][dm][rg] * inv_l);
      *reinterpret_cast<s16x4*>(ctx + base + dm * 16 + quad * 4) = pv;
    }
  }
}

// ---------------- out = partial0 + partial1 ----------------
__global__ __launch_bounds__(256) void add_out_kernel(const float* __restrict__ a,
                                                      const float* __restrict__ b,
                                                      float* __restrict__ o, int n) {
  int i = (blockIdx.x * 256 + threadIdx.x) * 4;
  if (i < n) {
    float4 x = *reinterpret_cast<const float4*>(a + i);
    float4 y = *reinterpret_cast<const float4*>(b + i);
    float4 r = {x.x + y.x, x.y + y.y, x.z + y.z, x.w + y.w};
    *reinterpret_cast<float4*>(o + i) = r;
  }
}

// ---------------- launch ----------------
extern "C" void kernel_launch(void* const* d_in, const int* in_sizes, int n_in,
                              void* d_out, int out_size, void* d_ws, size_t ws_size,
                              hipStream_t stream) {
  const float* x = (const float*)d_in[0];
  const float* Wq = (const float*)d_in[1];
  const float* Wkv = (const float*)d_in[2];
  const float* Wo = (const float*)d_in[3];
  const float* q_scale = (const float*)d_in[4];
  const float* k_scale = (const float*)d_in[5];
  float* out = (float*)d_out;

  char* ws = (char*)d_ws;
  size_t off = 0;
  auto alloc = [&](size_t bytes) {
    void* p = ws + off;
    off += (bytes + 255) & ~(size_t)255;
    return p;
  };
  unsigned short* xb = (unsigned short*)alloc((size_t)MROWS * DM * 2);
  unsigned short* wt1 = (unsigned short*)alloc((size_t)NQKV * DM * 2);   // [Wq^T ; Wkv^T]
  unsigned short* wot = (unsigned short*)alloc((size_t)DM * DM * 2);
  float* qkvp = (float*)alloc(2 * (size_t)MROWS * NQKV * 4);             // split-K partials
  unsigned short* qb = (unsigned short*)alloc((size_t)BATCH * NH * S_LEN * HD * 2);
  unsigned short* kbuf = (unsigned short*)alloc((size_t)BATCH * NKV * S_LEN * HD * 2);
  unsigned short* vt = (unsigned short*)alloc((size_t)BATCH * NKV * HD * S_LEN * 2);
  unsigned short* ctx = (unsigned short*)alloc((size_t)MROWS * DM * 2);
  float* outp = (float*)alloc(2 * (size_t)MROWS * DM * 4);               // split-K partials

  cvt_x_kernel<<<(MROWS * DM) / 1024, 256, 0, stream>>>(x, xb, MROWS * DM);
  transpose_cvt_kernel<<<dim3(16, 16), 256, 0, stream>>>(Wq, wt1, 1024, 1024);
  transpose_cvt_kernel<<<dim3(8, 16), 256, 0, stream>>>(Wkv, wt1 + 1024 * 1024, 1024, 512);
  transpose_cvt_kernel<<<dim3(16, 16), 256, 0, stream>>>(Wo, wot, 1024, 1024);

  gemm_bt_splitk<<<dim3(NQKV / 128, MROWS / 128, 2), 256, 0, stream>>>(xb, wt1, qkvp,
                                                                       MROWS, NQKV, 512, DM);

  norm_rope_kernel<<<(MROWS * 20) / 4, 256, 0, stream>>>(qkvp, q_scale, k_scale, qb, kbuf);
  v_transpose_kernel<<<256, 256, 0, stream>>>(qkvp, vt);

  attn_kernel<<<BATCH * NKV * (S_LEN / 32), 256, 0, stream>>>(qb, kbuf, vt, ctx);

  gemm_bt_splitk<<<dim3(DM / 128, MROWS / 128, 2), 256, 0, stream>>>(ctx, wot, outp,
                                                                     MROWS, DM, 512, DM);
  add_out_kernel<<<(MROWS * DM) / 1024, 256, 0, stream>>>(outp, outp + (size_t)MROWS * DM,
                                                          out, MROWS * DM);
}